// Round 14
// baseline (201.196 us; speedup 1.0000x reference)
//
#include <hip/hip_runtime.h>

namespace {
constexpr int T_STEPS = 50;
constexpr int BATCH_N = 131072;
constexpr int HIDDEN  = 100;
}

typedef unsigned int v2u __attribute__((ext_vector_type(2)));

#define REP100(X) \
  X(0) X(1) X(2) X(3) X(4) X(5) X(6) X(7) X(8) X(9) \
  X(10) X(11) X(12) X(13) X(14) X(15) X(16) X(17) X(18) X(19) \
  X(20) X(21) X(22) X(23) X(24) X(25) X(26) X(27) X(28) X(29) \
  X(30) X(31) X(32) X(33) X(34) X(35) X(36) X(37) X(38) X(39) \
  X(40) X(41) X(42) X(43) X(44) X(45) X(46) X(47) X(48) X(49) \
  X(50) X(51) X(52) X(53) X(54) X(55) X(56) X(57) X(58) X(59) \
  X(60) X(61) X(62) X(63) X(64) X(65) X(66) X(67) X(68) X(69) \
  X(70) X(71) X(72) X(73) X(74) X(75) X(76) X(77) X(78) X(79) \
  X(80) X(81) X(82) X(83) X(84) X(85) X(86) X(87) X(88) X(89) \
  X(90) X(91) X(92) X(93) X(94) X(95) X(96) X(97) X(98) X(99)

#define SNN_DECL(H) float mm##H = 0.0f;

// Bitwise-identical arithmetic to the R7/R10 PASS (recomputed spike,
// validated in R10):
//   cur = fmaf(x1, w1b, x0*w1a)
//   sp  = (m_old > 0.5f) ? 1 : 0
//   m   = fmaf(sp, -0.5f, fmaf(0.9f, m_old, cur))
//   sc  = (m > 0.5f) ? 1 : 0
//   acc0/acc1: strictly h-ascending serial fmaf chain
#define SNN_STEP(H) { \
    const float4 w = wp[H];                 /* LDS broadcast ds_read_b128 */ \
    const float cur = fmaf(x1, w.y, x0 * w.x); \
    const float sp  = (mm##H > 0.5f) ? 1.0f : 0.0f; \
    mm##H = fmaf(sp, -0.5f, fmaf(0.9f, mm##H, cur)); \
    const float sc  = (mm##H > 0.5f) ? 1.0f : 0.0f; \
    acc0 = fmaf(sc, w.z, acc0); \
    acc1 = fmaf(sc, w.w, acc1); }

__global__ __launch_bounds__(256, 2)   // pin 256-VGPR class (grid caps at 2 waves/SIMD anyway)
void snn_touter_lds2(const unsigned int* __restrict__ x_u,
                     const float* __restrict__ W1,
                     const float* __restrict__ W2,
                     unsigned int* __restrict__ out_u)
{
#pragma clang fp contract(off)
    __shared__ float4 sw4[HIDDEN];
    const int tid = threadIdx.x;
    if (tid < HIDDEN) {
        float4 w;
        w.x = W1[2 * tid];          // W1[h][0]
        w.y = W1[2 * tid + 1];      // W1[h][1]
        w.z = W2[tid];              // W2[0][h]
        w.w = W2[HIDDEN + tid];     // W2[1][h]
        sw4[tid] = w;
    }
    __syncthreads();

    const int b = blockIdx.x * 256 + tid;

    REP100(SNN_DECL)

    float M0 = 0.0f, M1 = 0.0f, S0 = 0.0f, S1 = 0.0f;   // layer-2 state
    const size_t mem_off = (size_t)T_STEPS * BATCH_N * 2;

    // Manual next-t x prefetch (issues ~900 instrs before use).
    float nx0 = __uint_as_float(x_u[(size_t)b * 2]);
    float nx1 = __uint_as_float(x_u[(size_t)b * 2 + 1]);

    unsigned lds_off = 0;   // laundered each t: defeats LICM/CSE hoisting
#pragma unroll 1
    for (int t = 0; t < T_STEPS; ++t) {
        asm volatile("" : "+v"(lds_off));
        const float4* wp = reinterpret_cast<const float4*>(
            reinterpret_cast<const char*>(sw4) + lds_off);

        const float x0 = nx0;
        const float x1 = nx1;
        if (t + 1 < T_STEPS) {
            const size_t ncell = ((size_t)(t + 1) * BATCH_N + b) * 2;
            nx0 = __uint_as_float(x_u[ncell]);
            nx1 = __uint_as_float(x_u[ncell + 1]);
        }

        float acc0 = 0.0f, acc1 = 0.0f;
        REP100(SNN_STEP)

        M0 = fmaf(S0, -0.5f, fmaf(0.9f, M0, acc0));
        M1 = fmaf(S1, -0.5f, fmaf(0.9f, M1, acc1));
        S0 = (M0 > 0.5f) ? 1.0f : 0.0f;
        S1 = (M1 > 0.5f) ? 1.0f : 0.0f;

        const size_t cell = ((size_t)t * BATCH_N + b) * 2;
        v2u sv; sv.x = __float_as_uint(S0); sv.y = __float_as_uint(S1);
        v2u mv; mv.x = __float_as_uint(M0); mv.y = __float_as_uint(M1);
        *reinterpret_cast<v2u*>(out_u + cell) = sv;
        *reinterpret_cast<v2u*>(out_u + mem_off + cell) = mv;
    }
}

extern "C" void kernel_launch(void* const* d_in, const int* in_sizes, int n_in,
                              void* d_out, int out_size, void* d_ws, size_t ws_size,
                              hipStream_t stream) {
    // Robust input mapping: x = the unique large buffer; W1 precedes W2 among
    // the rest (holds under both dict order [x,W1,W2] and sorted [W1,W2,x]).
    int big = 0;
    for (int i = 1; i < n_in; ++i) if (in_sizes[i] > in_sizes[big]) big = i;
    const void* ptrs[3] = {nullptr, nullptr, nullptr};  // x, W1, W2
    int k = 1;
    ptrs[0] = d_in[big];
    for (int i = 0; i < n_in; ++i) {
        if (i == big) continue;
        ptrs[k++] = d_in[i];
    }
    const unsigned int* x_u = (const unsigned int*)ptrs[0];
    const float* W1 = (const float*)ptrs[1];
    const float* W2 = (const float*)ptrs[2];
    unsigned int* out_u = (unsigned int*)d_out;
    hipLaunchKernelGGL(snn_touter_lds2, dim3(BATCH_N / 256), dim3(256), 0,
                       stream, x_u, W1, W2, out_u);
}

// Round 15
// 195.795 us; speedup vs baseline: 1.0276x; 1.0276x over previous
//
#include <hip/hip_runtime.h>

namespace {
constexpr int T_STEPS = 50;
constexpr int BATCH_N = 131072;
constexpr int HIDDEN  = 100;
}

typedef float v2f __attribute__((ext_vector_type(2)));
typedef unsigned int v2u __attribute__((ext_vector_type(2)));

// R7 skeleton (h-outer, t fully unrolled, x/acc staged in static arrays,
// 96% VALUBusy proven) with the h-pair packed into VOP3P f32 ops.
// Per-component arithmetic is bitwise-identical to the R7 PASS:
//   cur = fmaf(x1, w1b, x0*w1a)
//   m   = fmaf(0.9, m, cur); m = fmaf(s_prev, -0.5, m)
//   s   = (m > 0.5) ? 1 : 0
//   acc0/acc1 += s*w, strictly h-ascending (hA before hB)
__global__ __launch_bounds__(256)
void snn_pk2(const unsigned int* __restrict__ x_u,
             const float* __restrict__ W1,
             const float* __restrict__ W2,
             unsigned int* __restrict__ out_u)
{
#pragma clang fp contract(off)
    // Weight tables packed for pair use: per h, {w1a,w1b} and {w20,w21}.
    __shared__ v2f swl1[HIDDEN], swl2[HIDDEN];
    const int tid = threadIdx.x;
    if (tid < HIDDEN) {
        v2f a; a.x = W1[2 * tid]; a.y = W1[2 * tid + 1];
        v2f c; c.x = W2[tid];     c.y = W2[HIDDEN + tid];
        swl1[tid] = a;
        swl2[tid] = c;
    }
    __syncthreads();

    const int b = blockIdx.x * 256 + tid;

    // Stage x exactly as R7 (static arrays -> AGPR-resident).
    float x0[T_STEPS], x1[T_STEPS];
#pragma unroll
    for (int t = 0; t < T_STEPS; ++t) {
        const size_t cell = ((size_t)t * BATCH_N + b) * 2;
        x0[t] = __uint_as_float(x_u[cell]);
        x1[t] = __uint_as_float(x_u[cell + 1]);
    }

    // acc packed: .x = acc0 chain, .y = acc1 chain.
    v2f acc[T_STEPS];
#pragma unroll
    for (int t = 0; t < T_STEPS; ++t) acc[t] = (v2f){0.0f, 0.0f};

    const v2f K09 = {0.9f, 0.9f};
    const v2f KM5 = {-0.5f, -0.5f};

#pragma unroll 1
    for (int h = 0; h < HIDDEN; h += 2) {
        const v2f w1A = swl1[h];        // {w1a[hA], w1b[hA]}
        const v2f w1B = swl1[h + 1];
        const v2f w2A = swl2[h];        // {w20[hA], w21[hA]}
        const v2f w2B = swl2[h + 1];
        // Cross-pack layer-1 weights: {w1a[hA], w1a[hB]}, {w1b[hA], w1b[hB]}.
        const v2f wa = {w1A.x, w1B.x};
        const v2f wb = {w1A.y, w1B.y};

        v2f m = {0.0f, 0.0f};   // {mem1[hA], mem1[hB]}
        v2f s = {0.0f, 0.0f};   // {spk1[hA], spk1[hB]}

#pragma unroll
        for (int t = 0; t < T_STEPS; ++t) {
            const float u = x0[t];
            const float v = x1[t];
            const v2f uu = {u, u};
            const v2f vv = {v, v};

            v2f cur = __builtin_elementwise_fma(vv, wb, uu * wa);
            m = __builtin_elementwise_fma(K09, m, cur);
            m = __builtin_elementwise_fma(s, KM5, m);
            s.x = (m.x > 0.5f) ? 1.0f : 0.0f;
            s.y = (m.y > 0.5f) ? 1.0f : 0.0f;

            // h-ascending: hA's update then hB's (bitwise == R7 order).
            v2f a = acc[t];
            a = __builtin_elementwise_fma((v2f){s.x, s.x}, w2A, a);
            a = __builtin_elementwise_fma((v2f){s.y, s.y}, w2B, a);
            acc[t] = a;
        }
    }

    // Layer 2 recurrence + outputs (R7 verbatim, packed reads).
    const size_t mem_off = (size_t)T_STEPS * BATCH_N * 2;
    float M0 = 0.0f, M1 = 0.0f, S0 = 0.0f, S1 = 0.0f;
#pragma unroll
    for (int t = 0; t < T_STEPS; ++t) {
        M0 = fmaf(S0, -0.5f, fmaf(0.9f, M0, acc[t].x));
        M1 = fmaf(S1, -0.5f, fmaf(0.9f, M1, acc[t].y));
        S0 = (M0 > 0.5f) ? 1.0f : 0.0f;
        S1 = (M1 > 0.5f) ? 1.0f : 0.0f;
        const size_t cell = ((size_t)t * BATCH_N + b) * 2;
        out_u[cell]               = __float_as_uint(S0);
        out_u[cell + 1]           = __float_as_uint(S1);
        out_u[mem_off + cell]     = __float_as_uint(M0);
        out_u[mem_off + cell + 1] = __float_as_uint(M1);
    }
}

extern "C" void kernel_launch(void* const* d_in, const int* in_sizes, int n_in,
                              void* d_out, int out_size, void* d_ws, size_t ws_size,
                              hipStream_t stream) {
    // Robust input mapping: x = the unique large buffer; W1 precedes W2 among
    // the rest (holds under both dict order [x,W1,W2] and sorted [W1,W2,x]).
    int big = 0;
    for (int i = 1; i < n_in; ++i) if (in_sizes[i] > in_sizes[big]) big = i;
    const void* ptrs[3] = {nullptr, nullptr, nullptr};  // x, W1, W2
    int k = 1;
    ptrs[0] = d_in[big];
    for (int i = 0; i < n_in; ++i) {
        if (i == big) continue;
        ptrs[k++] = d_in[i];
    }
    const unsigned int* x_u = (const unsigned int*)ptrs[0];
    const float* W1 = (const float*)ptrs[1];
    const float* W2 = (const float*)ptrs[2];
    unsigned int* out_u = (unsigned int*)d_out;
    hipLaunchKernelGGL(snn_pk2, dim3(BATCH_N / 256), dim3(256), 0,
                       stream, x_u, W1, W2, out_u);
}